// Round 8
// baseline (571.533 us; speedup 1.0000x reference)
//
#include <hip/hip_runtime.h>

// ---------------------------------------------------------------------------
// ResBlock GNN layer on MI355X (gfx950). ALL tensors fp32.
//   h  = gelu(x @ W_ff1 + b)
//   h += seg_sum(gelu(P[src]+Q[dst]+R_e+b_mp)), P=h@Wa, Q=h@Wb, R=ef@Wc  (x2)
//   out = x + h @ W_ff2 + b
// R8: rgemm restructured for latency: NO __syncthreads (per-wave 8KB LDS
// region, wave-synchronous lgkmcnt ordering), 2 tiles per wave with both
// A-gathers issued up front (2 independent chains/wave). Everything else R7.
// ---------------------------------------------------------------------------

typedef __attribute__((ext_vector_type(8))) short short8;
typedef __attribute__((ext_vector_type(4))) float f32x4;

#define HD __device__ __forceinline__

HD unsigned short f2bf(float f) {
    unsigned int u = __float_as_uint(f);
    return (unsigned short)((u + 0x7fffu + ((u >> 16) & 1u)) >> 16);  // RNE
}
HD float lo16(unsigned int u) { return __uint_as_float(u << 16); }
HD float hi16(unsigned int u) { return __uint_as_float(u & 0xffff0000u); }

// gelu tanh-approx via sigmoid identity: 0.5(1+tanh(z)) == sigmoid(2z).
HD float gelu_f(float x) {
    float u = x * (-1.5957691216057308f - 0.07135481627f * (x * x));
    return x * __builtin_amdgcn_rcpf(1.f + __expf(u));
}

// ---------------------------------------------------------------------------
// All 8 weight repacks in one dispatch.
// ---------------------------------------------------------------------------
__global__ void repack_all(const float* __restrict__ Wff1,
                           const float* __restrict__ Wmp1,
                           const float* __restrict__ Wmp2,
                           const float* __restrict__ Wff2,
                           unsigned short* __restrict__ Bp) {
    const int begs[9] = {0, 65536, 131072, 196608, 212992, 278528, 344064,
                         360448, 425984};
    const int srcid[8] = {0, 1, 1, 1, 2, 2, 2, 3};
    const int rowoff[8] = {0, 0, 256, 512, 0, 256, 512, 0};
    int i = blockIdx.x * 256 + threadIdx.x;
    if (i >= 425984) return;
    int s = 0;
#pragma unroll
    for (int k = 1; k < 8; ++k)
        if (i >= begs[k]) s = k;
    const float* Ws[4] = {Wff1, Wmp1, Wmp2, Wff2};
    const float* B = Ws[srcid[s]];
    int local = i - begs[s];
    int k = local >> 8, n = local & 255;
    int kb = k >> 5, kr = k & 31;
    int quad = kr >> 3, j = kr & 7;
    int lane = quad * 16 + (n & 15);
    int nt = n >> 4;
    Bp[begs[s] + ((((kb * 16 + nt) * 64) + lane) << 3) + j] =
        f2bf(B[(size_t)(rowoff[s] + k) * 256 + n]);
}

// ---------------------------------------------------------------------------
// General LDS-free bf16 MFMA GEMM (64x64 tile, grid (ceil(M/64),4)) for FFNs.
// ---------------------------------------------------------------------------
__global__ __launch_bounds__(256) void gemm_kernel(
    const void* __restrict__ Av, int a_is_f32, int M, int K,
    const unsigned short* __restrict__ Bp,
    const float* __restrict__ bias, const float* __restrict__ resid,
    unsigned short* __restrict__ Cb, float* __restrict__ Cf, int do_gelu) {
    int lane = threadIdx.x & 63;
    int w = threadIdx.x >> 6;
    int row0 = blockIdx.x * 64 + w * 16;
    int n0 = blockIdx.y * 64;
    int m15 = lane & 15, quad = lane >> 4;

    int arow = row0 + m15;
    if (arow > M - 1) arow = M - 1;

    f32x4 acc[4] = {{0,0,0,0},{0,0,0,0},{0,0,0,0},{0,0,0,0}};
    const float* Af = (const float*)Av + (size_t)arow * K + quad * 8;
    const unsigned short* Ab = (const unsigned short*)Av + (size_t)arow * K + quad * 8;

    for (int kt = 0; kt < K; kt += 32) {
        short8 a;
        if (a_is_f32) {
            f32x4 lo = *(const f32x4*)(Af + kt);
            f32x4 hi = *(const f32x4*)(Af + kt + 4);
#pragma unroll
            for (int j = 0; j < 4; ++j) {
                a[j] = (short)f2bf(lo[j]);
                a[j + 4] = (short)f2bf(hi[j]);
            }
        } else {
            a = *(const short8*)(Ab + kt);
        }
        const unsigned short* bbase =
            Bp + ((((size_t)(kt >> 5) * 16 + (n0 >> 4)) * 64 + lane) << 3);
#pragma unroll
        for (int nt = 0; nt < 4; ++nt) {
            short8 b = *(const short8*)(bbase + nt * 64 * 8);
            acc[nt] = __builtin_amdgcn_mfma_f32_16x16x32_bf16(a, b, acc[nt], 0, 0, 0);
        }
    }

#pragma unroll
    for (int nt = 0; nt < 4; ++nt) {
        int col = n0 + nt * 16 + m15;
        float bv = bias ? bias[col] : 0.f;
#pragma unroll
        for (int r = 0; r < 4; ++r) {
            int row = row0 + quad * 4 + r;
            if (row < M) {
                float v = acc[nt][r] + bv;
                if (do_gelu) v = gelu_f(v);
                size_t idx = (size_t)row * 256 + col;
                if (resid) v += resid[idx];
                if (Cb) Cb[idx] = f2bf(v);
                if (Cf) Cf[idx] = v;
            }
        }
    }
}

// ---------------------------------------------------------------------------
// P and Q in one dispatch: grid ((M+63)/64, 8); y<4 -> P, y>=4 -> Q (+b_mp).
// ---------------------------------------------------------------------------
__global__ __launch_bounds__(256) void pq_kernel(
    const unsigned short* __restrict__ A, int M,
    const unsigned short* __restrict__ BpA, const unsigned short* __restrict__ BpB,
    const float* __restrict__ qbias,
    unsigned short* __restrict__ Pb, unsigned short* __restrict__ Qb) {
    int lane = threadIdx.x & 63;
    int w = threadIdx.x >> 6;
    int row0 = blockIdx.x * 64 + w * 16;
    int isQ = blockIdx.y >> 2;
    int n0 = (blockIdx.y & 3) * 64;
    const unsigned short* Bp = isQ ? BpB : BpA;
    unsigned short* out = isQ ? Qb : Pb;
    int m15 = lane & 15, quad = lane >> 4;

    int arow = row0 + m15;
    if (arow > M - 1) arow = M - 1;
    const unsigned short* Ab = A + (size_t)arow * 256 + quad * 8;

    f32x4 acc[4] = {{0,0,0,0},{0,0,0,0},{0,0,0,0},{0,0,0,0}};
    for (int kt = 0; kt < 256; kt += 32) {
        short8 a = *(const short8*)(Ab + kt);
        const unsigned short* bbase =
            Bp + ((((size_t)(kt >> 5) * 16 + (n0 >> 4)) * 64 + lane) << 3);
#pragma unroll
        for (int nt = 0; nt < 4; ++nt) {
            short8 b = *(const short8*)(bbase + nt * 64 * 8);
            acc[nt] = __builtin_amdgcn_mfma_f32_16x16x32_bf16(a, b, acc[nt], 0, 0, 0);
        }
    }

#pragma unroll
    for (int nt = 0; nt < 4; ++nt) {
        int col = n0 + nt * 16 + m15;
        float bv = isQ ? qbias[col] : 0.f;
#pragma unroll
        for (int r = 0; r < 4; ++r) {
            int row = row0 + quad * 4 + r;
            if (row < M) out[(size_t)row * 256 + col] = f2bf(acc[nt][r] + bv);
        }
    }
}

// ---------------------------------------------------------------------------
// R-GEMM v2: Rout[i] = bf16(ef[perm[i]] @ Wc), SORTED order. Block = 128 rows;
// wave w owns rows w*16..w*16+15 of each 64-row half (2 tiles). Per-wave 8KB
// LDS region, NO barriers (wave-synchronous lgkmcnt); both tiles' A-gathers
// issued up front for 2 independent latency chains per wave.
// ---------------------------------------------------------------------------
__global__ __launch_bounds__(256) void rgemm_kernel(
    const float* __restrict__ A, const int* __restrict__ perm, int Mlen,
    const unsigned short* __restrict__ BpC, unsigned short* __restrict__ Rout) {
    __shared__ unsigned short tile[4][16 * 256];  // 8 KB per wave
    int lane = threadIdx.x & 63;
    int w = threadIdx.x >> 6;
    int m15 = lane & 15, quad = lane >> 4;
    unsigned short* tw = tile[w];

    int row0[2];
    const float* Af[2];
#pragma unroll
    for (int t = 0; t < 2; ++t) {
        row0[t] = blockIdx.x * 128 + t * 64 + w * 16;
        int arow = row0[t] + m15;
        if (arow > Mlen - 1) arow = Mlen - 1;
        if (arow < 0) arow = 0;
        Af[t] = A + (size_t)perm[arow] * 64 + quad * 8;
    }
    // issue both tiles' A-gathers up front (independent chains)
    f32x4 raw[2][4];
#pragma unroll
    for (int t = 0; t < 2; ++t) {
        raw[t][0] = *(const f32x4*)(Af[t]);
        raw[t][1] = *(const f32x4*)(Af[t] + 4);
        raw[t][2] = *(const f32x4*)(Af[t] + 32);
        raw[t][3] = *(const f32x4*)(Af[t] + 36);
    }

#pragma unroll
    for (int t = 0; t < 2; ++t) {
        short8 av[2];
#pragma unroll
        for (int j = 0; j < 4; ++j) {
            av[0][j]     = (short)f2bf(raw[t][0][j]);
            av[0][j + 4] = (short)f2bf(raw[t][1][j]);
            av[1][j]     = (short)f2bf(raw[t][2][j]);
            av[1][j + 4] = (short)f2bf(raw[t][3][j]);
        }
        f32x4 acc[16];
#pragma unroll
        for (int i = 0; i < 16; ++i) acc[i] = {0.f, 0.f, 0.f, 0.f};
#pragma unroll
        for (int kb = 0; kb < 2; ++kb) {
            const unsigned short* bb = BpC + (((size_t)kb * 16 * 64 + lane) << 3);
#pragma unroll
            for (int nt = 0; nt < 16; ++nt) {
                short8 b = *(const short8*)(bb + (size_t)nt * 64 * 8);
                acc[nt] = __builtin_amdgcn_mfma_f32_16x16x32_bf16(av[kb], b, acc[nt], 0, 0, 0);
            }
        }
        // stage this wave's 16 rows (own region; lgkmcnt orders vs prior reads)
#pragma unroll
        for (int nt = 0; nt < 16; ++nt) {
            int col = nt * 16 + m15;
#pragma unroll
            for (int r = 0; r < 4; ++r)
                tw[(quad * 4 + r) * 256 + col] = f2bf(acc[nt][r]);
        }
        // bulk store own 16 rows: 512 uint4, 8 per lane, coalesced full lines
        int rows_left = Mlen - row0[t];
        if (rows_left > 0) {
            const uint4* tsrc = (const uint4*)tw;
            uint4* gdst = (uint4*)(Rout + (size_t)row0[t] * 256);
#pragma unroll
            for (int i = 0; i < 8; ++i) {
                int idx = i * 64 + lane;
                if ((idx >> 5) < rows_left) gdst[idx] = tsrc[idx];
            }
        }
    }
}

// ---------------------------------------------------------------------------
// Counting sort by dst: zero -> histogram -> single-block scan -> scatter.
// ---------------------------------------------------------------------------
__global__ void zero_i32(int* __restrict__ p, int n) {
    int i = blockIdx.x * 256 + threadIdx.x;
    if (i < n) p[i] = 0;
}
__global__ void hist_kernel(const int* __restrict__ dst, int* __restrict__ cnt, int E) {
    int e = blockIdx.x * 256 + threadIdx.x;
    if (e < E) atomicAdd(&cnt[dst[e]], 1);
}
__global__ __launch_bounds__(1024) void scan_kernel(const int* __restrict__ cnt,
                                                    int* __restrict__ cursor, int N) {
    __shared__ int part[1024];
    int tid = threadIdx.x;
    int per = (N + 1023) / 1024;
    int lo = tid * per;
    int s = 0;
    for (int j = 0; j < per; ++j) {
        int idx = lo + j;
        if (idx < N) s += cnt[idx];
    }
    part[tid] = s;
    __syncthreads();
    for (int off = 1; off < 1024; off <<= 1) {
        int t = (tid >= off) ? part[tid - off] : 0;
        __syncthreads();
        part[tid] += t;
        __syncthreads();
    }
    int run = (tid > 0) ? part[tid - 1] : 0;
    for (int j = 0; j < per; ++j) {
        int idx = lo + j;
        if (idx < N) {
            cursor[idx] = run;
            run += cnt[idx];
        }
    }
}
__global__ void scatter_kernel(const int* __restrict__ src, const int* __restrict__ dst,
                               int* __restrict__ cursor, int* __restrict__ perm,
                               int* __restrict__ srcs, int E) {
    int e = blockIdx.x * 256 + threadIdx.x;
    if (e < E) {
        int pos = atomicAdd(&cursor[dst[e]], 1);
        perm[pos] = e;
        srcs[pos] = src[e];
    }
}

// ---------------------------------------------------------------------------
// Node kernel: wave per node; lane owns 4 channels. R sequential (sorted),
// P via scalar-addressed gather, Q has bias folded. No LDS/barriers/atomics.
// ---------------------------------------------------------------------------
__global__ __launch_bounds__(256) void node_kernel(
    const unsigned short* __restrict__ Pb, const unsigned short* __restrict__ Qb,
    const unsigned short* __restrict__ Rbuf, const int* __restrict__ srcs,
    const int* __restrict__ cursor, const int* __restrict__ cnt,
    float* __restrict__ Hacc, unsigned short* __restrict__ h_bf,
    int N, int off, int len, int store_f32, int write_h) {
    int lane = threadIdx.x & 63;
    int w = threadIdx.x >> 6;
    int d = blockIdx.x * 4 + w;
    if (d >= N) return;
    int c0 = lane << 2;
    size_t nidx = ((size_t)d << 8) + c0;
    float4 acc = *(const float4*)(Hacc + nidx);

    int end = cursor[d];
    int beg = end - cnt[d];
    if (beg < off) beg = off;
    int e2 = end;
    if (e2 > off + len) e2 = off + len;

    if (beg < e2) {
        uint2 qu = *(const uint2*)(Qb + nidx);
        float q0 = lo16(qu.x), q1 = hi16(qu.x);
        float q2 = lo16(qu.y), q3 = hi16(qu.y);
        const unsigned short* Rrow = Rbuf + (((size_t)(beg - off)) << 8) + c0;
        int pos = beg;
        for (; pos + 8 <= e2; pos += 8, Rrow += 8 * 256) {
#pragma unroll
            for (int k = 0; k < 8; ++k) {
                int s = __builtin_amdgcn_readfirstlane(srcs[pos + k]);
                uint2 pu = *(const uint2*)(Pb + (((size_t)s) << 8) + c0);
                uint2 ru = *(const uint2*)(Rrow + (size_t)k * 256);
                acc.x += gelu_f(lo16(pu.x) + q0 + lo16(ru.x));
                acc.y += gelu_f(hi16(pu.x) + q1 + hi16(ru.x));
                acc.z += gelu_f(lo16(pu.y) + q2 + lo16(ru.y));
                acc.w += gelu_f(hi16(pu.y) + q3 + hi16(ru.y));
            }
        }
        for (; pos < e2; ++pos, Rrow += 256) {
            int s = __builtin_amdgcn_readfirstlane(srcs[pos]);
            uint2 pu = *(const uint2*)(Pb + (((size_t)s) << 8) + c0);
            uint2 ru = *(const uint2*)(Rrow);
            acc.x += gelu_f(lo16(pu.x) + q0 + lo16(ru.x));
            acc.y += gelu_f(hi16(pu.x) + q1 + hi16(ru.x));
            acc.z += gelu_f(lo16(pu.y) + q2 + lo16(ru.y));
            acc.w += gelu_f(hi16(pu.y) + q3 + hi16(ru.y));
        }
    }
    if (store_f32) *(float4*)(Hacc + nidx) = acc;
    if (write_h) {
        uint2 o;
        o.x = (unsigned int)f2bf(acc.x) | ((unsigned int)f2bf(acc.y) << 16);
        o.y = (unsigned int)f2bf(acc.z) | ((unsigned int)f2bf(acc.w) << 16);
        *(uint2*)(h_bf + nidx) = o;
    }
}

// ---------------------------------------------------------------------------
extern "C" void kernel_launch(void* const* d_in, const int* in_sizes, int n_in,
                              void* d_out, int out_size, void* d_ws, size_t ws_size,
                              hipStream_t stream) {
    const float* x     = (const float*)d_in[0];
    const int*   ei    = (const int*)d_in[1];
    const float* ef    = (const float*)d_in[2];
    const float* W_ff1 = (const float*)d_in[3];
    const float* b_ff1 = (const float*)d_in[4];
    const float* W_mp1 = (const float*)d_in[5];
    const float* b_mp1 = (const float*)d_in[6];
    const float* W_mp2 = (const float*)d_in[7];
    const float* b_mp2 = (const float*)d_in[8];
    const float* W_ff2 = (const float*)d_in[9];
    const float* b_ff2 = (const float*)d_in[10];

    const int N = in_sizes[0] / 256;  // 10000
    const int E = in_sizes[1] / 2;    // 320000
    const int* src = ei;
    const int* dst = ei + E;

    // ---- workspace carve (256B-aligned bumps) ----
    char* p = (char*)d_ws;
    unsigned short* h_bf = (unsigned short*)p;  p += ((size_t)N * 256 * 2 + 255) & ~255ull;
    unsigned short* Pbuf = (unsigned short*)p;  p += ((size_t)N * 256 * 2 + 255) & ~255ull;
    unsigned short* Qbuf = (unsigned short*)p;  p += ((size_t)N * 256 * 2 + 255) & ~255ull;
    float* Hacc = (float*)p;                    p += ((size_t)N * 256 * 4 + 255) & ~255ull;
    unsigned short* Bp = (unsigned short*)p;    p += (425984ull * 2 + 255) & ~255ull;
    int* cnt    = (int*)p;                      p += ((size_t)N * 4 + 255) & ~255ull;
    int* cursor = (int*)p;                      p += ((size_t)N * 4 + 255) & ~255ull;
    int* perm   = (int*)p;                      p += ((size_t)E * 4 + 255) & ~255ull;
    int* srcs   = (int*)p;                      p += ((size_t)E * 4 + 255) & ~255ull;
    unsigned short* Rbuf = (unsigned short*)p;  // bf16, sorted order

    long long remain = (long long)ws_size - (long long)(p - (char*)d_ws);
    long long chunk = remain / 512;  // 256 bf16 per edge row
    chunk -= (chunk % 128);
    if (chunk > E) chunk = E;
    if (chunk < 128) chunk = 128;

    unsigned short* Bp_ff1 = Bp + 0;
    unsigned short* Bp_a1  = Bp + 65536;
    unsigned short* Bp_b1  = Bp + 131072;
    unsigned short* Bp_c1  = Bp + 196608;
    unsigned short* Bp_a2  = Bp + 212992;
    unsigned short* Bp_b2  = Bp + 278528;
    unsigned short* Bp_c2  = Bp + 344064;
    unsigned short* Bp_ff2 = Bp + 360448;

    // ---- repack all weights (single dispatch) ----
    repack_all<<<1664, 256, 0, stream>>>(W_ff1, W_mp1, W_mp2, W_ff2, Bp);

    // ---- counting sort of edges by dst (CSR) ----
    zero_i32<<<(N + 255) / 256, 256, 0, stream>>>(cnt, N);
    hist_kernel<<<(E + 255) / 256, 256, 0, stream>>>(dst, cnt, E);
    scan_kernel<<<1, 1024, 0, stream>>>(cnt, cursor, N);
    scatter_kernel<<<(E + 255) / 256, 256, 0, stream>>>(src, dst, cursor, perm, srcs, E);

    dim3 gN((N + 63) / 64, 4);
    dim3 gPQ((N + 63) / 64, 8);

    // ---- FFN1: h = gelu(x@W_ff1 + b); h_bf for GEMMs, Hacc = residual base
    gemm_kernel<<<gN, 256, 0, stream>>>(x, 1, N, 256, Bp_ff1, b_ff1, nullptr,
                                        h_bf, Hacc, 1);

    const unsigned short* Bp_a[2] = {Bp_a1, Bp_a2};
    const unsigned short* Bp_b[2] = {Bp_b1, Bp_b2};
    const unsigned short* Bp_c[2] = {Bp_c1, Bp_c2};
    const float* bmp[2] = {b_mp1, b_mp2};

    for (int l = 0; l < 2; ++l) {
        pq_kernel<<<gPQ, 256, 0, stream>>>(h_bf, N, Bp_a[l], Bp_b[l], bmp[l],
                                           Pbuf, Qbuf);
        for (long long off = 0; off < E; off += chunk) {
            int len = (int)((E - off < chunk) ? (E - off) : chunk);
            int last = (off + len >= E);
            rgemm_kernel<<<(len + 127) / 128, 256, 0, stream>>>(
                ef, perm + off, len, Bp_c[l], Rbuf);
            node_kernel<<<(N + 3) / 4, 256, 0, stream>>>(
                Pbuf, Qbuf, Rbuf, srcs, cursor, cnt, Hacc, h_bf,
                N, (int)off, len, (l == 0) || !last, last);
        }
    }

    // ---- FFN2: out = x + h@W_ff2 + b ----
    gemm_kernel<<<gN, 256, 0, stream>>>(h_bf, 0, N, 256, Bp_ff2, b_ff2, x,
                                        nullptr, (float*)d_out, 0);
}